// Round 1
// baseline (645.039 us; speedup 1.0000x reference)
//
#include <hip/hip_runtime.h>
#include <hip/hip_bf16.h>

typedef __bf16 bf16;
typedef __bf16 bf16x8 __attribute__((ext_vector_type(8)));
typedef float f32x4 __attribute__((ext_vector_type(4)));

#define QSCALE 0.18033688011112042f  /* (1/8) * log2(e) : folds softmax scale into Wq */

// ---- async global->LDS (16B per lane, wave-uniform LDS base + lane*16) ----
__device__ __forceinline__ void load_lds16(const void* gp, void* lp) {
  __builtin_amdgcn_global_load_lds((const __attribute__((address_space(1))) void*)gp,
                                   (__attribute__((address_space(3))) void*)lp, 16, 0, 0);
}

// ---------------------------------------------------------------------------
// Kernel T: x [B,C,N] fp32 -> t [B,N,C] bf16   (B=32, C=640, N=1024)
// ---------------------------------------------------------------------------
__global__ __launch_bounds__(256) void k_transpose(const float* __restrict__ x,
                                                   bf16* __restrict__ t) {
  __shared__ float tile[64][65];
  const int b = blockIdx.z, c0 = blockIdx.y * 64, n0 = blockIdx.x * 64;
  const int tid = threadIdx.x, lx = tid & 63, ly = tid >> 6;
  const float* xp = x + ((size_t)b * 640 + c0) * 1024 + n0;
#pragma unroll
  for (int i = 0; i < 16; ++i) {
    int c = i * 4 + ly;
    tile[c][lx] = xp[(size_t)c * 1024 + lx];
  }
  __syncthreads();
  bf16* tp = t + ((size_t)b * 1024 + n0) * 640 + c0;
#pragma unroll
  for (int i = 0; i < 16; ++i) {
    int n = i * 4 + ly;
    tp[(size_t)n * 640 + lx] = (bf16)tile[lx][n];
  }
}

// ---------------------------------------------------------------------------
// Kernel Wc: cast one weight matrix [1024,640] fp32 -> bf16 (optionally scaled)
// ---------------------------------------------------------------------------
__global__ __launch_bounds__(256) void k_castw(const float* __restrict__ w,
                                               bf16* __restrict__ dst, float s) {
  int i = blockIdx.x * 256 + threadIdx.x;
  if (i < 655360) dst[i] = (bf16)(w[i] * s);
}

// ---------------------------------------------------------------------------
// Kernel P: C[32768 x 3072] = A[32768 x 640] * B[3072 x 640]^T  (bf16 in, bf16 out)
// 128x128 tile, BK=64, 4 waves (2x2), 16x16x32 MFMA, global_load_lds + XOR swizzle.
// Epilogue scatters into q/k/v [BH=512][N=1024][64] bf16.
// ---------------------------------------------------------------------------
__global__ __launch_bounds__(256) void k_gemm_qkv(const bf16* __restrict__ A,
                                                  const bf16* __restrict__ Bw,
                                                  bf16* __restrict__ qkv) {
  __shared__ __align__(16) bf16 As[128 * 64];
  __shared__ __align__(16) bf16 Bs[128 * 64];
  const int tid = threadIdx.x;
  const int lane = tid & 63;
  const int w = tid >> 6;
  const int wm = w & 1, wn = w >> 1;
  const int g = lane >> 4, ln = lane & 15;
  const int m0 = blockIdx.x * 128;
  const int n0 = blockIdx.y * 128;

  f32x4 acc[4][4];
#pragma unroll
  for (int i = 0; i < 4; ++i)
#pragma unroll
    for (int j = 0; j < 4; ++j)
#pragma unroll
      for (int r = 0; r < 4; ++r) acc[i][j][r] = 0.f;

  for (int k0 = 0; k0 < 640; k0 += 64) {
    // stage A and B tiles: 1024 16B-chunks each; chunk c holds global (m=c>>3, kq=(c&7)^(m&7))
#pragma unroll
    for (int it = 0; it < 4; ++it) {
      int c = it * 256 + w * 64 + lane;
      int m = c >> 3;
      int kq = (c & 7) ^ (m & 7);
      load_lds16(A + (size_t)(m0 + m) * 640 + (k0 + kq * 8), As + (size_t)(it * 256 + w * 64) * 8);
      load_lds16(Bw + (size_t)(n0 + m) * 640 + (k0 + kq * 8), Bs + (size_t)(it * 256 + w * 64) * 8);
    }
    __syncthreads();
#pragma unroll
    for (int kk = 0; kk < 2; ++kk) {
      bf16x8 af[4], bfr[4];
#pragma unroll
      for (int mi = 0; mi < 4; ++mi) {
        int m = wm * 64 + mi * 16 + ln;
        int cc = m * 8 + ((kk * 4 + g) ^ (m & 7));
        af[mi] = *(const bf16x8*)(As + cc * 8);
      }
#pragma unroll
      for (int ni = 0; ni < 4; ++ni) {
        int n = wn * 64 + ni * 16 + ln;
        int cc = n * 8 + ((kk * 4 + g) ^ (n & 7));
        bfr[ni] = *(const bf16x8*)(Bs + cc * 8);
      }
#pragma unroll
      for (int mi = 0; mi < 4; ++mi)
#pragma unroll
        for (int ni = 0; ni < 4; ++ni)
          acc[mi][ni] = __builtin_amdgcn_mfma_f32_16x16x32_bf16(af[mi], bfr[ni], acc[mi][ni], 0, 0, 0);
    }
    __syncthreads();
  }

  // epilogue: D layout col=lane&15, row=(lane>>4)*4+r  -> scatter to q/k/v [bh][n][d]
#pragma unroll
  for (int mi = 0; mi < 4; ++mi)
#pragma unroll
    for (int ni = 0; ni < 4; ++ni)
#pragma unroll
      for (int r = 0; r < 4; ++r) {
        int row = m0 + wm * 64 + mi * 16 + g * 4 + r;   // (b,n)
        int col = n0 + wn * 64 + ni * 16 + ln;          // (which,h,d)
        int bb = row >> 10, n = row & 1023;
        int which = col >> 10, h = (col >> 6) & 15, d = col & 63;
        qkv[(size_t)which * 33554432 +
            ((((size_t)bb * 16 + h) * 1024 + n) * 64 + d)] = (bf16)acc[mi][ni][r];
      }
}

// ---------------------------------------------------------------------------
// Kernel A: fused two-pass attention column-weights.
// grid (itile=4, bh=512), 256 thr = 4 waves, wave owns 64 q-rows.
// Pass 1: l_i = sum_j exp2(s_ij)  (q pre-scaled by scale*log2e)
// Pass 2: w_j += sum_i exp2(s_ij) / l_i   via atomicAdd.
// ---------------------------------------------------------------------------
__global__ __launch_bounds__(256) void k_attn(const bf16* __restrict__ q,
                                              const bf16* __restrict__ kmat,
                                              float* __restrict__ wsum) {
  const int bh = blockIdx.y;
  const int it = blockIdx.x;
  const int tid = threadIdx.x;
  const int lane = tid & 63;
  const int w = tid >> 6;
  const int g = lane >> 4, ln = lane & 15;
  const bf16* qb = q + (size_t)bh * 65536;
  const bf16* kb = kmat + (size_t)bh * 65536;
  const int i0 = it * 256 + w * 64;

  // Q fragments: A-layout m=lane&15, k=(lane>>4)*8+j ; held in regs for both passes
  bf16x8 qf[4][2];
#pragma unroll
  for (int mi = 0; mi < 4; ++mi)
#pragma unroll
    for (int kc = 0; kc < 2; ++kc)
      qf[mi][kc] = *(const bf16x8*)(qb + (size_t)(i0 + mi * 16 + ln) * 64 + kc * 32 + g * 8);

  float rs[4][4];
#pragma unroll
  for (int mi = 0; mi < 4; ++mi)
#pragma unroll
    for (int r = 0; r < 4; ++r) rs[mi][r] = 0.f;

  // ---- pass 1: row sums ----
  for (int jt = 0; jt < 16; ++jt) {
    bf16x8 kf[4][2];
#pragma unroll
    for (int ni = 0; ni < 4; ++ni)
#pragma unroll
      for (int kc = 0; kc < 2; ++kc)
        kf[ni][kc] = *(const bf16x8*)(kb + (size_t)(jt * 64 + ni * 16 + ln) * 64 + kc * 32 + g * 8);
#pragma unroll
    for (int mi = 0; mi < 4; ++mi)
#pragma unroll
      for (int ni = 0; ni < 4; ++ni) {
        f32x4 s = {0.f, 0.f, 0.f, 0.f};
        s = __builtin_amdgcn_mfma_f32_16x16x32_bf16(qf[mi][0], kf[ni][0], s, 0, 0, 0);
        s = __builtin_amdgcn_mfma_f32_16x16x32_bf16(qf[mi][1], kf[ni][1], s, 0, 0, 0);
#pragma unroll
        for (int r = 0; r < 4; ++r) rs[mi][r] += exp2f(s[r]);
      }
  }
  // reduce row sums across the 16 lanes sharing g (cols live in lane&15)
  float rinv[4][4];
#pragma unroll
  for (int mi = 0; mi < 4; ++mi)
#pragma unroll
    for (int r = 0; r < 4; ++r) {
      float v = rs[mi][r];
      v += __shfl_xor(v, 1);
      v += __shfl_xor(v, 2);
      v += __shfl_xor(v, 4);
      v += __shfl_xor(v, 8);
      rinv[mi][r] = 1.0f / v;
    }

  // ---- pass 2: column sums scaled by 1/l_i ----
  for (int jt = 0; jt < 16; ++jt) {
    bf16x8 kf[4][2];
#pragma unroll
    for (int ni = 0; ni < 4; ++ni)
#pragma unroll
      for (int kc = 0; kc < 2; ++kc)
        kf[ni][kc] = *(const bf16x8*)(kb + (size_t)(jt * 64 + ni * 16 + ln) * 64 + kc * 32 + g * 8);
    float cs[4] = {0.f, 0.f, 0.f, 0.f};
#pragma unroll
    for (int mi = 0; mi < 4; ++mi)
#pragma unroll
      for (int ni = 0; ni < 4; ++ni) {
        f32x4 s = {0.f, 0.f, 0.f, 0.f};
        s = __builtin_amdgcn_mfma_f32_16x16x32_bf16(qf[mi][0], kf[ni][0], s, 0, 0, 0);
        s = __builtin_amdgcn_mfma_f32_16x16x32_bf16(qf[mi][1], kf[ni][1], s, 0, 0, 0);
#pragma unroll
        for (int r = 0; r < 4; ++r) cs[ni] += exp2f(s[r]) * rinv[mi][r];
      }
#pragma unroll
    for (int ni = 0; ni < 4; ++ni) {
      float v = cs[ni];
      v += __shfl_xor(v, 16);
      v += __shfl_xor(v, 32);
      if (g == 0) atomicAdd(wsum + (size_t)bh * 1024 + jt * 64 + ni * 16 + ln, v);
    }
  }
}

// ---------------------------------------------------------------------------
// Kernel F: out[bh][d] = LN_d( (1/N) * sum_j w[bh][j] * V[bh][j][d] )
// ---------------------------------------------------------------------------
__global__ __launch_bounds__(256) void k_final(const float* __restrict__ wsum,
                                               const bf16* __restrict__ v,
                                               const float* __restrict__ gamma,
                                               const float* __restrict__ beta,
                                               float* __restrict__ out) {
  const int bh = blockIdx.x;
  const int tid = threadIdx.x;
  const int d = tid & 63, part = tid >> 6;
  const bf16* vb = v + (size_t)bh * 65536;
  const float* wb = wsum + (size_t)bh * 1024;
  float acc = 0.f;
  for (int j = part * 256; j < part * 256 + 256; ++j)
    acc += wb[j] * (float)vb[(size_t)j * 64 + d];
  __shared__ float red[4][64];
  red[part][d] = acc;
  __syncthreads();
  if (tid < 64) {
    float y = (red[0][d] + red[1][d] + red[2][d] + red[3][d]) * (1.0f / 1024.0f);
    float s1 = y;
#pragma unroll
    for (int off = 1; off < 64; off <<= 1) s1 += __shfl_xor(s1, off);
    float mu = s1 * (1.0f / 64.0f);
    float dy = y - mu;
    float s2 = dy * dy;
#pragma unroll
    for (int off = 1; off < 64; off <<= 1) s2 += __shfl_xor(s2, off);
    float rstd = rsqrtf(s2 * (1.0f / 64.0f) + 1e-5f);
    out[(size_t)bh * 64 + d] = dy * rstd * gamma[d] + beta[d];
  }
}

// ---------------------------------------------------------------------------
extern "C" void kernel_launch(void* const* d_in, const int* in_sizes, int n_in,
                              void* d_out, int out_size, void* d_ws, size_t ws_size,
                              hipStream_t stream) {
  const float* x     = (const float*)d_in[0];
  const float* Wq    = (const float*)d_in[1];
  const float* Wk    = (const float*)d_in[2];
  const float* Wv    = (const float*)d_in[3];
  const float* gamma = (const float*)d_in[4];
  const float* beta  = (const float*)d_in[5];
  float* out = (float*)d_out;

  char* ws = (char*)d_ws;
  bf16*  tbf  = (bf16*)ws;                    // 32768*640*2      = 41,943,040 B
  bf16*  wbf  = (bf16*)(ws + 41943040);       // 3072*640*2       =  3,932,160 B
  bf16*  qkv  = (bf16*)(ws + 45875200);       // 3*512*1024*64*2  = 201,326,592 B
  float* wsum = (float*)(ws + 247201792);     // 512*1024*4       =  2,097,152 B

  hipMemsetAsync(wsum, 0, (size_t)512 * 1024 * sizeof(float), stream);
  k_transpose<<<dim3(16, 10, 32), 256, 0, stream>>>(x, tbf);
  k_castw<<<2560, 256, 0, stream>>>(Wq, wbf, QSCALE);
  k_castw<<<2560, 256, 0, stream>>>(Wk, wbf + 655360, 1.0f);
  k_castw<<<2560, 256, 0, stream>>>(Wv, wbf + 1310720, 1.0f);
  k_gemm_qkv<<<dim3(256, 24), 256, 0, stream>>>(tbf, wbf, qkv);
  k_attn<<<dim3(4, 512), 256, 0, stream>>>(qkv, qkv + 33554432, wsum);
  k_final<<<512, 256, 0, stream>>>(wsum, qkv + 67108864, gamma, beta, out);
}

// Round 2
// 569.226 us; speedup vs baseline: 1.1332x; 1.1332x over previous
//
#include <hip/hip_runtime.h>
#include <hip/hip_bf16.h>

typedef __bf16 bf16;
typedef __bf16 bf16x8 __attribute__((ext_vector_type(8)));
typedef float f32x4 __attribute__((ext_vector_type(4)));

#define QSCALE 0.18033688011112042f  /* (1/8) * log2(e) : folds softmax scale into Wq */

// raw v_exp_f32 (exp2). Inputs here are |x| <~ 2.5 so no edge-case handling needed.
#define EXP2(x) __builtin_amdgcn_exp2f(x)

// ---- async global->LDS (16B per lane, wave-uniform LDS base + lane*16) ----
__device__ __forceinline__ void load_lds16(const void* gp, void* lp) {
  __builtin_amdgcn_global_load_lds((const __attribute__((address_space(1))) void*)gp,
                                   (__attribute__((address_space(3))) void*)lp, 16, 0, 0);
}

// ---------------------------------------------------------------------------
// Kernel T: x [B,C,N] fp32 -> t [B,N,C] bf16   (B=32, C=640, N=1024)
// ---------------------------------------------------------------------------
__global__ __launch_bounds__(256) void k_transpose(const float* __restrict__ x,
                                                   bf16* __restrict__ t) {
  __shared__ float tile[64][65];
  const int b = blockIdx.z, c0 = blockIdx.y * 64, n0 = blockIdx.x * 64;
  const int tid = threadIdx.x, lx = tid & 63, ly = tid >> 6;
  const float* xp = x + ((size_t)b * 640 + c0) * 1024 + n0;
#pragma unroll
  for (int i = 0; i < 16; ++i) {
    int c = i * 4 + ly;
    tile[c][lx] = xp[(size_t)c * 1024 + lx];
  }
  __syncthreads();
  bf16* tp = t + ((size_t)b * 1024 + n0) * 640 + c0;
#pragma unroll
  for (int i = 0; i < 16; ++i) {
    int n = i * 4 + ly;
    tp[(size_t)n * 640 + lx] = (bf16)tile[lx][n];
  }
}

// ---------------------------------------------------------------------------
// Kernel Wc: cast one weight matrix [1024,640] fp32 -> bf16 (optionally scaled)
// ---------------------------------------------------------------------------
__global__ __launch_bounds__(256) void k_castw(const float* __restrict__ w,
                                               bf16* __restrict__ dst, float s) {
  int i = blockIdx.x * 256 + threadIdx.x;
  if (i < 655360) dst[i] = (bf16)(w[i] * s);
}

// ---------------------------------------------------------------------------
// Kernel P: C[32768 x 3072] = A[32768 x 640] * B[3072 x 640]^T  (bf16 in, bf16 out)
// 128x128 tile, BK=64, 4 waves (2x2), 16x16x32 MFMA, global_load_lds + XOR swizzle.
// Epilogue scatters into q/k/v [BH=512][N=1024][64] bf16.
// ---------------------------------------------------------------------------
__global__ __launch_bounds__(256) void k_gemm_qkv(const bf16* __restrict__ A,
                                                  const bf16* __restrict__ Bw,
                                                  bf16* __restrict__ qkv) {
  __shared__ __align__(16) bf16 As[128 * 64];
  __shared__ __align__(16) bf16 Bs[128 * 64];
  const int tid = threadIdx.x;
  const int lane = tid & 63;
  const int w = tid >> 6;
  const int wm = w & 1, wn = w >> 1;
  const int g = lane >> 4, ln = lane & 15;
  const int m0 = blockIdx.x * 128;
  const int n0 = blockIdx.y * 128;

  f32x4 acc[4][4];
#pragma unroll
  for (int i = 0; i < 4; ++i)
#pragma unroll
    for (int j = 0; j < 4; ++j)
#pragma unroll
      for (int r = 0; r < 4; ++r) acc[i][j][r] = 0.f;

  for (int k0 = 0; k0 < 640; k0 += 64) {
    // stage A and B tiles: 1024 16B-chunks each; chunk c holds global (m=c>>3, kq=(c&7)^(m&7))
#pragma unroll
    for (int it = 0; it < 4; ++it) {
      int c = it * 256 + w * 64 + lane;
      int m = c >> 3;
      int kq = (c & 7) ^ (m & 7);
      load_lds16(A + (size_t)(m0 + m) * 640 + (k0 + kq * 8), As + (size_t)(it * 256 + w * 64) * 8);
      load_lds16(Bw + (size_t)(n0 + m) * 640 + (k0 + kq * 8), Bs + (size_t)(it * 256 + w * 64) * 8);
    }
    __syncthreads();
#pragma unroll
    for (int kk = 0; kk < 2; ++kk) {
      bf16x8 af[4], bfr[4];
#pragma unroll
      for (int mi = 0; mi < 4; ++mi) {
        int m = wm * 64 + mi * 16 + ln;
        int cc = m * 8 + ((kk * 4 + g) ^ (m & 7));
        af[mi] = *(const bf16x8*)(As + cc * 8);
      }
#pragma unroll
      for (int ni = 0; ni < 4; ++ni) {
        int n = wn * 64 + ni * 16 + ln;
        int cc = n * 8 + ((kk * 4 + g) ^ (n & 7));
        bfr[ni] = *(const bf16x8*)(Bs + cc * 8);
      }
#pragma unroll
      for (int mi = 0; mi < 4; ++mi)
#pragma unroll
        for (int ni = 0; ni < 4; ++ni)
          acc[mi][ni] = __builtin_amdgcn_mfma_f32_16x16x32_bf16(af[mi], bfr[ni], acc[mi][ni], 0, 0, 0);
    }
    __syncthreads();
  }

  // epilogue: D layout col=lane&15, row=(lane>>4)*4+r  -> scatter to q/k/v [bh][n][d]
#pragma unroll
  for (int mi = 0; mi < 4; ++mi)
#pragma unroll
    for (int ni = 0; ni < 4; ++ni)
#pragma unroll
      for (int r = 0; r < 4; ++r) {
        int row = m0 + wm * 64 + mi * 16 + g * 4 + r;   // (b,n)
        int col = n0 + wn * 64 + ni * 16 + ln;          // (which,h,d)
        int bb = row >> 10, n = row & 1023;
        int which = col >> 10, h = (col >> 6) & 15, d = col & 63;
        qkv[(size_t)which * 33554432 +
            ((((size_t)bb * 16 + h) * 1024 + n) * 64 + d)] = (bf16)acc[mi][ni][r];
      }
}

// ---------------------------------------------------------------------------
// Kernel A: fused two-pass attention column-weights.
// grid (itile=4, bh=512), 256 thr = 4 waves, wave owns 64 q-rows.
// Pass 1: l_i = sum_j exp2(s_ij)  (q pre-scaled by scale*log2e)
// Pass 2: w_j += sum_i exp2(s_ij) / l_i   via atomicAdd.
// ---------------------------------------------------------------------------
__global__ __launch_bounds__(256) void k_attn(const bf16* __restrict__ q,
                                              const bf16* __restrict__ kmat,
                                              float* __restrict__ wsum) {
  const int bh = blockIdx.y;
  const int it = blockIdx.x;
  const int tid = threadIdx.x;
  const int lane = tid & 63;
  const int w = tid >> 6;
  const int g = lane >> 4, ln = lane & 15;
  const bf16* qb = q + (size_t)bh * 65536;
  const bf16* kb = kmat + (size_t)bh * 65536;
  const int i0 = it * 256 + w * 64;

  // Q fragments: A-layout m=lane&15, k=(lane>>4)*8+j ; held in regs for both passes
  bf16x8 qf[4][2];
#pragma unroll
  for (int mi = 0; mi < 4; ++mi)
#pragma unroll
    for (int kc = 0; kc < 2; ++kc)
      qf[mi][kc] = *(const bf16x8*)(qb + (size_t)(i0 + mi * 16 + ln) * 64 + kc * 32 + g * 8);

  float rs[4][4];
#pragma unroll
  for (int mi = 0; mi < 4; ++mi)
#pragma unroll
    for (int r = 0; r < 4; ++r) rs[mi][r] = 0.f;

  // ---- pass 1: row sums ----
  for (int jt = 0; jt < 16; ++jt) {
    bf16x8 kf[4][2];
#pragma unroll
    for (int ni = 0; ni < 4; ++ni)
#pragma unroll
      for (int kc = 0; kc < 2; ++kc)
        kf[ni][kc] = *(const bf16x8*)(kb + (size_t)(jt * 64 + ni * 16 + ln) * 64 + kc * 32 + g * 8);
#pragma unroll
    for (int mi = 0; mi < 4; ++mi)
#pragma unroll
      for (int ni = 0; ni < 4; ++ni) {
        f32x4 s = {0.f, 0.f, 0.f, 0.f};
        s = __builtin_amdgcn_mfma_f32_16x16x32_bf16(qf[mi][0], kf[ni][0], s, 0, 0, 0);
        s = __builtin_amdgcn_mfma_f32_16x16x32_bf16(qf[mi][1], kf[ni][1], s, 0, 0, 0);
#pragma unroll
        for (int r = 0; r < 4; ++r) rs[mi][r] += EXP2(s[r]);
      }
  }
  // reduce row sums across the 16 lanes sharing g (cols live in lane&15)
  float rinv[4][4];
#pragma unroll
  for (int mi = 0; mi < 4; ++mi)
#pragma unroll
    for (int r = 0; r < 4; ++r) {
      float v = rs[mi][r];
      v += __shfl_xor(v, 1);
      v += __shfl_xor(v, 2);
      v += __shfl_xor(v, 4);
      v += __shfl_xor(v, 8);
      rinv[mi][r] = 1.0f / v;
    }

  // ---- pass 2: column sums scaled by 1/l_i ----
  for (int jt = 0; jt < 16; ++jt) {
    bf16x8 kf[4][2];
#pragma unroll
    for (int ni = 0; ni < 4; ++ni)
#pragma unroll
      for (int kc = 0; kc < 2; ++kc)
        kf[ni][kc] = *(const bf16x8*)(kb + (size_t)(jt * 64 + ni * 16 + ln) * 64 + kc * 32 + g * 8);
    float cs[4] = {0.f, 0.f, 0.f, 0.f};
#pragma unroll
    for (int mi = 0; mi < 4; ++mi)
#pragma unroll
      for (int ni = 0; ni < 4; ++ni) {
        f32x4 s = {0.f, 0.f, 0.f, 0.f};
        s = __builtin_amdgcn_mfma_f32_16x16x32_bf16(qf[mi][0], kf[ni][0], s, 0, 0, 0);
        s = __builtin_amdgcn_mfma_f32_16x16x32_bf16(qf[mi][1], kf[ni][1], s, 0, 0, 0);
#pragma unroll
        for (int r = 0; r < 4; ++r) cs[ni] += EXP2(s[r]) * rinv[mi][r];
      }
#pragma unroll
    for (int ni = 0; ni < 4; ++ni) {
      float v = cs[ni];
      v += __shfl_xor(v, 16);
      v += __shfl_xor(v, 32);
      if (g == 0) atomicAdd(wsum + (size_t)bh * 1024 + jt * 64 + ni * 16 + ln, v);
    }
  }
}

// ---------------------------------------------------------------------------
// Kernel F: out[bh][d] = LN_d( (1/N) * sum_j w[bh][j] * V[bh][j][d] )
// ---------------------------------------------------------------------------
__global__ __launch_bounds__(256) void k_final(const float* __restrict__ wsum,
                                               const bf16* __restrict__ v,
                                               const float* __restrict__ gamma,
                                               const float* __restrict__ beta,
                                               float* __restrict__ out) {
  const int bh = blockIdx.x;
  const int tid = threadIdx.x;
  const int d = tid & 63, part = tid >> 6;
  const bf16* vb = v + (size_t)bh * 65536;
  const float* wb = wsum + (size_t)bh * 1024;
  float acc = 0.f;
  for (int j = part * 256; j < part * 256 + 256; ++j)
    acc += wb[j] * (float)vb[(size_t)j * 64 + d];
  __shared__ float red[4][64];
  red[part][d] = acc;
  __syncthreads();
  if (tid < 64) {
    float y = (red[0][d] + red[1][d] + red[2][d] + red[3][d]) * (1.0f / 1024.0f);
    float s1 = y;
#pragma unroll
    for (int off = 1; off < 64; off <<= 1) s1 += __shfl_xor(s1, off);
    float mu = s1 * (1.0f / 64.0f);
    float dy = y - mu;
    float s2 = dy * dy;
#pragma unroll
    for (int off = 1; off < 64; off <<= 1) s2 += __shfl_xor(s2, off);
    float rstd = rsqrtf(s2 * (1.0f / 64.0f) + 1e-5f);
    out[(size_t)bh * 64 + d] = dy * rstd * gamma[d] + beta[d];
  }
}

// ---------------------------------------------------------------------------
extern "C" void kernel_launch(void* const* d_in, const int* in_sizes, int n_in,
                              void* d_out, int out_size, void* d_ws, size_t ws_size,
                              hipStream_t stream) {
  const float* x     = (const float*)d_in[0];
  const float* Wq    = (const float*)d_in[1];
  const float* Wk    = (const float*)d_in[2];
  const float* Wv    = (const float*)d_in[3];
  const float* gamma = (const float*)d_in[4];
  const float* beta  = (const float*)d_in[5];
  float* out = (float*)d_out;

  char* ws = (char*)d_ws;
  bf16*  tbf  = (bf16*)ws;                    // 32768*640*2      = 41,943,040 B
  bf16*  wbf  = (bf16*)(ws + 41943040);       // 3072*640*2       =  3,932,160 B
  bf16*  qkv  = (bf16*)(ws + 45875200);       // 3*512*1024*64*2  = 201,326,592 B
  float* wsum = (float*)(ws + 247201792);     // 512*1024*4       =  2,097,152 B

  hipMemsetAsync(wsum, 0, (size_t)512 * 1024 * sizeof(float), stream);
  k_transpose<<<dim3(16, 10, 32), 256, 0, stream>>>(x, tbf);
  k_castw<<<2560, 256, 0, stream>>>(Wq, wbf, QSCALE);
  k_castw<<<2560, 256, 0, stream>>>(Wk, wbf + 655360, 1.0f);
  k_castw<<<2560, 256, 0, stream>>>(Wv, wbf + 1310720, 1.0f);
  k_gemm_qkv<<<dim3(256, 24), 256, 0, stream>>>(tbf, wbf, qkv);
  k_attn<<<dim3(4, 512), 256, 0, stream>>>(qkv, qkv + 33554432, wsum);
  k_final<<<512, 256, 0, stream>>>(wsum, qkv + 67108864, gamma, beta, out);
}